// Round 10
// baseline (133.327 us; speedup 1.0000x reference)
//
#include <hip/hip_runtime.h>
#include <hip/hip_bf16.h>

#define NGROUP 256   // B * (SEQ/TG)
#define NSLOT  128   // experts * sets
#define TG     32    // tokens per group
#define DM     1024  // model dim
#define FF     32    // expert size

#define LSCALE     4096.0f
#define INV_LSCALE (1.0f / 4096.0f)

typedef unsigned int  uint;
typedef unsigned short ushort;
typedef __attribute__((ext_vector_type(4))) float f32x4;
typedef __attribute__((ext_vector_type(8))) short bf16x8;
typedef __attribute__((ext_vector_type(8))) _Float16 f16x8;

__device__ __forceinline__ ushort f2bf(float f) {
    uint u = __float_as_uint(f);
    u += 0x7FFFu + ((u >> 16) & 1u);   // RNE
    return (ushort)(u >> 16);
}
__device__ __forceinline__ uint pk2(float a, float b) {
    return (uint)f2bf(a) | ((uint)f2bf(b) << 16);
}

// ---------------------------------------------------------------------------
// K1 mega-kernel (unchanged from v9): one launch, three block families.
//  blocks 0..511    : logits + tie-broken argmax + fused x->bf16 cast
//  blocks 512..767  : f1 -> f1F bf16 (MFMA-B fragment order)
//  blocks 768..1279 : f2 -> f2T[es][d][f] bf16
// ---------------------------------------------------------------------------
__global__ __launch_bounds__(256) void k_fused1(
    const float* __restrict__ x, const float* __restrict__ ctrl,
    const float* __restrict__ f1, const float* __restrict__ f2,
    int* __restrict__ idx, ushort* __restrict__ xb,
    ushort* __restrict__ f1F, ushort* __restrict__ f2T)
{
    __shared__ float smem[4 * 32 * 64];   // 32 KB
    const int t = threadIdx.x;

    if (blockIdx.x < 512) {
        float* Lp = smem;
        const int g  = blockIdx.x >> 1;
        const int nh = blockIdx.x & 1;
        const int w = t >> 6;
        const int lane = t & 63;
        const int lrow = lane & 15;
        const int lk8 = (lane >> 4) * 8;

        const size_t xoff0 = ((size_t)g * TG + lrow) * DM + w * 256 + lk8;
        const float* xr0 = x + xoff0;
        const float* xr1 = xr0 + 16 * DM;

        f32x4 ahh[2][4], ax[2][4];
#pragma unroll
        for (int mt = 0; mt < 2; ++mt)
#pragma unroll
            for (int nt = 0; nt < 4; ++nt) {
                ahh[mt][nt] = (f32x4){0.f, 0.f, 0.f, 0.f};
                ax[mt][nt]  = (f32x4){0.f, 0.f, 0.f, 0.f};
            }

        for (int ks = 0; ks < 8; ++ks) {
            f16x8 Ah[2], Al[2];
#pragma unroll
            for (int mt = 0; mt < 2; ++mt) {
                const float* p = (mt ? xr1 : xr0) + ks * 32;
                float xe[8];
                *(float4*)&xe[0] = *(const float4*)p;
                *(float4*)&xe[4] = *(const float4*)(p + 4);
                union { f16x8 v; _Float16 e[8]; } H, L;
#pragma unroll
                for (int j = 0; j < 8; ++j) {
                    const _Float16 h = (_Float16)xe[j];
                    H.e[j] = h;
                    L.e[j] = (_Float16)((xe[j] - (float)h) * LSCALE);
                }
                Ah[mt] = H.v; Al[mt] = L.v;
                if (nh == 0) {
                    uint4 o;
                    o.x = pk2(xe[0], xe[1]); o.y = pk2(xe[2], xe[3]);
                    o.z = pk2(xe[4], xe[5]); o.w = pk2(xe[6], xe[7]);
                    *(uint4*)(xb + xoff0 + (size_t)mt * 16 * DM + ks * 32) = o;
                }
            }
            const int kslice = w * 8 + ks;
#pragma unroll
            for (int nt = 0; nt < 4; ++nt) {
                const float* cp = ctrl
                    + (size_t)(kslice * 32 + ((lane >> 4) << 3)) * NSLOT
                    + nh * 64 + nt * 16 + (lane & 15);
                union { f16x8 v; _Float16 e[8]; } BH, BL;
#pragma unroll
                for (int j = 0; j < 8; ++j) {
                    const float c = cp[(size_t)j * NSLOT];
                    const _Float16 h = (_Float16)c;
                    BH.e[j] = h;
                    BL.e[j] = (_Float16)((c - (float)h) * LSCALE);
                }
#pragma unroll
                for (int mt = 0; mt < 2; ++mt) {
                    ahh[mt][nt] = __builtin_amdgcn_mfma_f32_16x16x32_f16(Ah[mt], BH.v, ahh[mt][nt], 0, 0, 0);
                    ax[mt][nt]  = __builtin_amdgcn_mfma_f32_16x16x32_f16(Al[mt], BH.v, ax[mt][nt], 0, 0, 0);
                    ax[mt][nt]  = __builtin_amdgcn_mfma_f32_16x16x32_f16(Ah[mt], BL.v, ax[mt][nt], 0, 0, 0);
                }
            }
        }

#pragma unroll
        for (int mt = 0; mt < 2; ++mt)
#pragma unroll
            for (int nt = 0; nt < 4; ++nt)
#pragma unroll
                for (int r = 0; r < 4; ++r) {
                    const int trow = mt * 16 + (lane >> 4) * 4 + r;
                    const int nl = nt * 16 + lrow;
                    Lp[(w * TG + trow) * 64 + nl] =
                        ahh[mt][nt][r] + ax[mt][nt][r] * INV_LSCALE;
                }
        __syncthreads();

        for (int i = t * 4; i < TG * 64; i += 256 * 4) {
            f32x4 s0 = *(const f32x4*)&Lp[i];
            f32x4 s1 = *(const f32x4*)&Lp[2048 + i];
            f32x4 s2 = *(const f32x4*)&Lp[4096 + i];
            f32x4 s3 = *(const f32x4*)&Lp[6144 + i];
            *(f32x4*)&Lp[i] = (s0 + s1) + (s2 + s3);
        }
        __syncthreads();

        if (t < 64) {
            const int n = t;
            float best = -1e30f;
            int bi = 0;
#pragma unroll
            for (int tt = 0; tt < TG; ++tt) {
                const float v = Lp[tt * 64 + n] + (float)tt * (1e-6f / 31.0f);
                if (v >= best) { best = v; bi = tt; }   // later token wins ties
            }
            idx[g * NSLOT + nh * 64 + n] = bi;
        }
    } else if (blockIdx.x < 768) {
        float* Ltr = smem;   // [64][33]
        const int i1 = blockIdx.x - 512;
        const int es = i1 >> 1;
        const int dh = i1 & 1;
        for (int d0 = dh * 512; d0 < dh * 512 + 512; d0 += 64) {
            const int dd = t >> 2, f0 = (t & 3) * 8;
            const float* src = f1 + (size_t)(d0 + dd) * 4096 + es * FF + f0;
            float4 a = *(const float4*)src;
            float4 b = *(const float4*)(src + 4);
            __syncthreads();
            float* Lq = &Ltr[dd * 33 + f0];
            Lq[0] = a.x; Lq[1] = a.y; Lq[2] = a.z; Lq[3] = a.w;
            Lq[4] = b.x; Lq[5] = b.y; Lq[6] = b.z; Lq[7] = b.w;
            __syncthreads();
            const int f = t & 31, koct = t >> 5;
            const int nt = f >> 4;
            const int kg = d0 + koct * 8;
            const int kslice = kg >> 5;
            const int lane2 = (f & 15) | (((kg >> 3) & 3) << 4);
            uint4 o;
            o.x = pk2(Ltr[(koct * 8 + 0) * 33 + f], Ltr[(koct * 8 + 1) * 33 + f]);
            o.y = pk2(Ltr[(koct * 8 + 2) * 33 + f], Ltr[(koct * 8 + 3) * 33 + f]);
            o.z = pk2(Ltr[(koct * 8 + 4) * 33 + f], Ltr[(koct * 8 + 5) * 33 + f]);
            o.w = pk2(Ltr[(koct * 8 + 6) * 33 + f], Ltr[(koct * 8 + 7) * 33 + f]);
            *(uint4*)(f1F + ((((size_t)es * 2 + nt) * 32 + kslice) * 64 + lane2) * 8) = o;
        }
    } else {
        float* Ltr = smem;   // [64][33]
        const int i2 = blockIdx.x - 768;
        const int es = i2 >> 2;
        const int dq = i2 & 3;
        for (int d0 = dq * 256; d0 < dq * 256 + 256; d0 += 64) {
            const int f = t >> 3, ds = (t & 7) * 8;
            const float* src = f2 + (size_t)es * (FF * DM) + f * DM + d0 + ds;
            float4 a = *(const float4*)src;
            float4 b = *(const float4*)(src + 4);
            __syncthreads();
            Ltr[(ds + 0) * 33 + f] = a.x; Ltr[(ds + 1) * 33 + f] = a.y;
            Ltr[(ds + 2) * 33 + f] = a.z; Ltr[(ds + 3) * 33 + f] = a.w;
            Ltr[(ds + 4) * 33 + f] = b.x; Ltr[(ds + 5) * 33 + f] = b.y;
            Ltr[(ds + 6) * 33 + f] = b.z; Ltr[(ds + 7) * 33 + f] = b.w;
            __syncthreads();
            const int dd = t >> 2, f0 = (t & 3) * 8;
            uint4 o;
            o.x = pk2(Ltr[dd * 33 + f0 + 0], Ltr[dd * 33 + f0 + 1]);
            o.y = pk2(Ltr[dd * 33 + f0 + 2], Ltr[dd * 33 + f0 + 3]);
            o.z = pk2(Ltr[dd * 33 + f0 + 4], Ltr[dd * 33 + f0 + 5]);
            o.w = pk2(Ltr[dd * 33 + f0 + 6], Ltr[dd * 33 + f0 + 7]);
            *(uint4*)(f2T + (size_t)es * (FF * DM) + (d0 + dd) * FF + f0) = o;
        }
    }
}

// ---------------------------------------------------------------------------
// K2: H = relu(x_gathered @ f1 + bias) via MFMA. LDS-free. UNCHANGED.
// ---------------------------------------------------------------------------
__global__ __launch_bounds__(256) void k_h_mfma(
    const ushort* __restrict__ xb, const ushort* __restrict__ f1F,
    const float* __restrict__ bias, const int* __restrict__ idx,
    ushort* __restrict__ Hb)
{
    const int es = blockIdx.x >> 2;
    const int gq = blockIdx.x & 3;
    const int w = threadIdx.x >> 6;
    const int lane = threadIdx.x & 63;
    const int lrow = lane & 15;
    const int lk8 = (lane >> 4) * 8;

    const int ga = gq * 64 + w * 16 + lrow;
    const int tok = idx[ga * NSLOT + es];
    const ushort* abase = xb + ((size_t)ga * TG + tok) * DM + lk8;
    const ushort* bbase = f1F + (size_t)es * 2 * 32 * 512 + (size_t)lane * 8;

    f32x4 acc[2] = {(f32x4){0.f, 0.f, 0.f, 0.f}, (f32x4){0.f, 0.f, 0.f, 0.f}};

#pragma unroll 4
    for (int kslice = 0; kslice < 32; ++kslice) {
        const bf16x8 A = *(const bf16x8*)(abase + kslice * 32);
#pragma unroll
        for (int nt = 0; nt < 2; ++nt) {
            const bf16x8 B = *(const bf16x8*)(bbase + ((size_t)nt * 32 + kslice) * 512);
            acc[nt] = __builtin_amdgcn_mfma_f32_16x16x32_bf16(A, B, acc[nt], 0, 0, 0);
        }
    }

#pragma unroll
    for (int nt = 0; nt < 2; ++nt) {
        const int f = nt * 16 + lrow;
        const float bv = bias[es * FF + f];
#pragma unroll
        for (int r = 0; r < 4; ++r) {
            const int g = gq * 64 + w * 16 + (lane >> 4) * 4 + r;
            const float hv = fmaxf(acc[nt][r] + bv, 0.0f);
            Hb[(size_t)g * (NSLOT * FF) + es * FF + f] = f2bf(hv);
        }
    }
}

// ---------------------------------------------------------------------------
// K3 (restructured): es-chain split 4x across waves, private OL planes.
// grid = 64 db x 64 go = 4096 blocks (db-major for f2T L2 locality),
// 256 thr (4 waves), static LDS 34 KB -> 4 blocks/CU (16 waves/CU).
// Block (db, go): d-16-tile D0 = db*16, groups G0 = go*4.
// Wave w owns es in [w*32, w*32+32): per es one MFMA
//   A = f2T[es][D0+row][f] (M=16 d), B = Hb rows for 4 groups dup x4 (N=16);
// D col = lane&15 -> group (col&3), rows = d quad. RMW into private plane
// OL[w][g][t][16] (chain length 32, no inter-wave aliasing; x4-dup lanes
// write identical values to the same address - benign, proven in v9).
// Epilogue: planes (p0+p1)+(p2+p3) -> dense coalesced store.
// ---------------------------------------------------------------------------
__global__ __launch_bounds__(256, 4) void k_out_mfma(
    const ushort* __restrict__ Hb, const ushort* __restrict__ f2T,
    const int* __restrict__ idx, float* __restrict__ out)
{
    __shared__ float OL[4 * 4 * 32 * 16];   // [w][g][t][16] = 32 KB
    __shared__ int idxs[NSLOT * 4];         // [es][g] = 2 KB

    const int db = blockIdx.x >> 6;
    const int go = blockIdx.x & 63;
    const int G0 = go * 4;
    const int D0 = db * 16;
    const int tid = threadIdx.x;
    const int w = tid >> 6;
    const int lane = tid & 63;
    const int gl = lane & 15;     // A: d-row; B/D: col -> group = gl&3
    const int g4 = gl & 3;
    const int lk8 = (lane >> 4) * 8;

    for (int i = tid * 4; i < 4 * 4 * 32 * 16; i += 1024)
        *(f32x4*)&OL[i] = (f32x4){0.f, 0.f, 0.f, 0.f};
    for (int i = tid; i < NSLOT * 4; i += 256)
        idxs[i] = idx[(G0 + (i & 3)) * NSLOT + (i >> 2)];
    __syncthreads();

    const int es0 = w * 32;
    const ushort* ap = f2T + (size_t)es0 * (FF * DM) + (size_t)(D0 + gl) * FF + lk8;
    const ushort* bp = Hb + (size_t)(G0 + g4) * (NSLOT * FF) + es0 * FF + lk8;
    float* olw = &OL[(w * 4 + g4) * (TG * 16) + (lane >> 4) * 4];
    const int* ixw = idxs + es0 * 4 + g4;

#pragma unroll 4
    for (int e = 0; e < 32; ++e) {
        const bf16x8 afr = *(const bf16x8*)(ap + (size_t)e * (FF * DM));
        const bf16x8 bfr = *(const bf16x8*)(bp + e * FF);
        const f32x4 d = __builtin_amdgcn_mfma_f32_16x16x32_bf16(
            afr, bfr, (f32x4){0.f, 0.f, 0.f, 0.f}, 0, 0, 0);
        const int t = ixw[e * 4];
        float* olp = olw + t * 16;
        *(f32x4*)olp = *(const f32x4*)olp + d;
    }
    __syncthreads();

    // reduce 4 planes, dense coalesced store: 4g x 32t x 16d = 512 f32x4
#pragma unroll
    for (int s = 0; s < 2; ++s) {
        const int q = tid + s * 256;
        const int g = q >> 7;
        const int t = (q >> 2) & 31;
        const int dq = (q & 3) * 4;
        const int o = (g * TG + t) * 16 + dq;
        const f32x4 v0 = *(const f32x4*)&OL[o];
        const f32x4 v1 = *(const f32x4*)&OL[o + 2048];
        const f32x4 v2 = *(const f32x4*)&OL[o + 4096];
        const f32x4 v3 = *(const f32x4*)&OL[o + 6144];
        *(f32x4*)&out[((size_t)(G0 + g) * TG + t) * DM + D0 + dq] =
            (v0 + v1) + (v2 + v3);
    }
}

// ---------------------------------------------------------------------------
extern "C" void kernel_launch(void* const* d_in, const int* in_sizes, int n_in,
                              void* d_out, int out_size, void* d_ws, size_t ws_size,
                              hipStream_t stream) {
    (void)in_sizes; (void)n_in; (void)out_size; (void)ws_size;
    const float* x    = (const float*)d_in[0];
    const float* ctrl = (const float*)d_in[1];
    const float* f1   = (const float*)d_in[2];
    const float* bias = (const float*)d_in[3];
    const float* f2   = (const float*)d_in[4];
    float* out = (float*)d_out;

    char* ws = (char*)d_ws;
    int*    idx = (int*)ws;                         // 128 KB
    ushort* Hb  = (ushort*)(ws + 131072);           // 2 MB
    ushort* f1F = (ushort*)(ws + 2228224);          // 8 MB
    ushort* f2T = (ushort*)(ws + 10616832);         // 8 MB
    ushort* xb  = (ushort*)(ws + 19005440);         // 16 MB (end ~34 MB)

    k_fused1<<<1280, 256, 0, stream>>>(x, ctrl, f1, f2, idx, xb, f1F, f2T);

    k_h_mfma<<<NSLOT * 4, 256, 0, stream>>>(xb, f1F, bias, idx, Hb);

    k_out_mfma<<<64 * 64, 256, 0, stream>>>(Hb, f2T, idx, out);
}

// Round 11
// 94.893 us; speedup vs baseline: 1.4050x; 1.4050x over previous
//
#include <hip/hip_runtime.h>
#include <hip/hip_bf16.h>

#define NGROUP 256   // B * (SEQ/TG)
#define NSLOT  128   // experts * sets
#define TG     32    // tokens per group
#define DM     1024  // model dim
#define FF     32    // expert size

#define LSCALE     4096.0f
#define INV_LSCALE (1.0f / 4096.0f)

typedef unsigned int  uint;
typedef unsigned short ushort;
typedef __attribute__((ext_vector_type(4))) float f32x4;
typedef __attribute__((ext_vector_type(8))) short bf16x8;
typedef __attribute__((ext_vector_type(8))) _Float16 f16x8;

__device__ __forceinline__ ushort f2bf(float f) {
    uint u = __float_as_uint(f);
    u += 0x7FFFu + ((u >> 16) & 1u);   // RNE
    return (ushort)(u >> 16);
}
__device__ __forceinline__ uint pk2(float a, float b) {
    return (uint)f2bf(a) | ((uint)f2bf(b) << 16);
}

// ---------------------------------------------------------------------------
// K1 mega-kernel (unchanged from v9): one launch, three block families.
//  blocks 0..511    : logits + tie-broken argmax + fused x->bf16 cast
//  blocks 512..767  : f1 -> f1F bf16 (MFMA-B fragment order)
//  blocks 768..1279 : f2 -> f2T[es][d][f] bf16
// ---------------------------------------------------------------------------
__global__ __launch_bounds__(256) void k_fused1(
    const float* __restrict__ x, const float* __restrict__ ctrl,
    const float* __restrict__ f1, const float* __restrict__ f2,
    int* __restrict__ idx, ushort* __restrict__ xb,
    ushort* __restrict__ f1F, ushort* __restrict__ f2T)
{
    __shared__ float smem[4 * 32 * 64];   // 32 KB
    const int t = threadIdx.x;

    if (blockIdx.x < 512) {
        float* Lp = smem;
        const int g  = blockIdx.x >> 1;
        const int nh = blockIdx.x & 1;
        const int w = t >> 6;
        const int lane = t & 63;
        const int lrow = lane & 15;
        const int lk8 = (lane >> 4) * 8;

        const size_t xoff0 = ((size_t)g * TG + lrow) * DM + w * 256 + lk8;
        const float* xr0 = x + xoff0;
        const float* xr1 = xr0 + 16 * DM;

        f32x4 ahh[2][4], ax[2][4];
#pragma unroll
        for (int mt = 0; mt < 2; ++mt)
#pragma unroll
            for (int nt = 0; nt < 4; ++nt) {
                ahh[mt][nt] = (f32x4){0.f, 0.f, 0.f, 0.f};
                ax[mt][nt]  = (f32x4){0.f, 0.f, 0.f, 0.f};
            }

        for (int ks = 0; ks < 8; ++ks) {
            f16x8 Ah[2], Al[2];
#pragma unroll
            for (int mt = 0; mt < 2; ++mt) {
                const float* p = (mt ? xr1 : xr0) + ks * 32;
                float xe[8];
                *(float4*)&xe[0] = *(const float4*)p;
                *(float4*)&xe[4] = *(const float4*)(p + 4);
                union { f16x8 v; _Float16 e[8]; } H, L;
#pragma unroll
                for (int j = 0; j < 8; ++j) {
                    const _Float16 h = (_Float16)xe[j];
                    H.e[j] = h;
                    L.e[j] = (_Float16)((xe[j] - (float)h) * LSCALE);
                }
                Ah[mt] = H.v; Al[mt] = L.v;
                if (nh == 0) {
                    uint4 o;
                    o.x = pk2(xe[0], xe[1]); o.y = pk2(xe[2], xe[3]);
                    o.z = pk2(xe[4], xe[5]); o.w = pk2(xe[6], xe[7]);
                    *(uint4*)(xb + xoff0 + (size_t)mt * 16 * DM + ks * 32) = o;
                }
            }
            const int kslice = w * 8 + ks;
#pragma unroll
            for (int nt = 0; nt < 4; ++nt) {
                const float* cp = ctrl
                    + (size_t)(kslice * 32 + ((lane >> 4) << 3)) * NSLOT
                    + nh * 64 + nt * 16 + (lane & 15);
                union { f16x8 v; _Float16 e[8]; } BH, BL;
#pragma unroll
                for (int j = 0; j < 8; ++j) {
                    const float c = cp[(size_t)j * NSLOT];
                    const _Float16 h = (_Float16)c;
                    BH.e[j] = h;
                    BL.e[j] = (_Float16)((c - (float)h) * LSCALE);
                }
#pragma unroll
                for (int mt = 0; mt < 2; ++mt) {
                    ahh[mt][nt] = __builtin_amdgcn_mfma_f32_16x16x32_f16(Ah[mt], BH.v, ahh[mt][nt], 0, 0, 0);
                    ax[mt][nt]  = __builtin_amdgcn_mfma_f32_16x16x32_f16(Al[mt], BH.v, ax[mt][nt], 0, 0, 0);
                    ax[mt][nt]  = __builtin_amdgcn_mfma_f32_16x16x32_f16(Ah[mt], BL.v, ax[mt][nt], 0, 0, 0);
                }
            }
        }

#pragma unroll
        for (int mt = 0; mt < 2; ++mt)
#pragma unroll
            for (int nt = 0; nt < 4; ++nt)
#pragma unroll
                for (int r = 0; r < 4; ++r) {
                    const int trow = mt * 16 + (lane >> 4) * 4 + r;
                    const int nl = nt * 16 + lrow;
                    Lp[(w * TG + trow) * 64 + nl] =
                        ahh[mt][nt][r] + ax[mt][nt][r] * INV_LSCALE;
                }
        __syncthreads();

        for (int i = t * 4; i < TG * 64; i += 256 * 4) {
            f32x4 s0 = *(const f32x4*)&Lp[i];
            f32x4 s1 = *(const f32x4*)&Lp[2048 + i];
            f32x4 s2 = *(const f32x4*)&Lp[4096 + i];
            f32x4 s3 = *(const f32x4*)&Lp[6144 + i];
            *(f32x4*)&Lp[i] = (s0 + s1) + (s2 + s3);
        }
        __syncthreads();

        if (t < 64) {
            const int n = t;
            float best = -1e30f;
            int bi = 0;
#pragma unroll
            for (int tt = 0; tt < TG; ++tt) {
                const float v = Lp[tt * 64 + n] + (float)tt * (1e-6f / 31.0f);
                if (v >= best) { best = v; bi = tt; }   // later token wins ties
            }
            idx[g * NSLOT + nh * 64 + n] = bi;
        }
    } else if (blockIdx.x < 768) {
        float* Ltr = smem;   // [64][33]
        const int i1 = blockIdx.x - 512;
        const int es = i1 >> 1;
        const int dh = i1 & 1;
        for (int d0 = dh * 512; d0 < dh * 512 + 512; d0 += 64) {
            const int dd = t >> 2, f0 = (t & 3) * 8;
            const float* src = f1 + (size_t)(d0 + dd) * 4096 + es * FF + f0;
            float4 a = *(const float4*)src;
            float4 b = *(const float4*)(src + 4);
            __syncthreads();
            float* Lq = &Ltr[dd * 33 + f0];
            Lq[0] = a.x; Lq[1] = a.y; Lq[2] = a.z; Lq[3] = a.w;
            Lq[4] = b.x; Lq[5] = b.y; Lq[6] = b.z; Lq[7] = b.w;
            __syncthreads();
            const int f = t & 31, koct = t >> 5;
            const int nt = f >> 4;
            const int kg = d0 + koct * 8;
            const int kslice = kg >> 5;
            const int lane2 = (f & 15) | (((kg >> 3) & 3) << 4);
            uint4 o;
            o.x = pk2(Ltr[(koct * 8 + 0) * 33 + f], Ltr[(koct * 8 + 1) * 33 + f]);
            o.y = pk2(Ltr[(koct * 8 + 2) * 33 + f], Ltr[(koct * 8 + 3) * 33 + f]);
            o.z = pk2(Ltr[(koct * 8 + 4) * 33 + f], Ltr[(koct * 8 + 5) * 33 + f]);
            o.w = pk2(Ltr[(koct * 8 + 6) * 33 + f], Ltr[(koct * 8 + 7) * 33 + f]);
            *(uint4*)(f1F + ((((size_t)es * 2 + nt) * 32 + kslice) * 64 + lane2) * 8) = o;
        }
    } else {
        float* Ltr = smem;   // [64][33]
        const int i2 = blockIdx.x - 768;
        const int es = i2 >> 2;
        const int dq = i2 & 3;
        for (int d0 = dq * 256; d0 < dq * 256 + 256; d0 += 64) {
            const int f = t >> 3, ds = (t & 7) * 8;
            const float* src = f2 + (size_t)es * (FF * DM) + f * DM + d0 + ds;
            float4 a = *(const float4*)src;
            float4 b = *(const float4*)(src + 4);
            __syncthreads();
            Ltr[(ds + 0) * 33 + f] = a.x; Ltr[(ds + 1) * 33 + f] = a.y;
            Ltr[(ds + 2) * 33 + f] = a.z; Ltr[(ds + 3) * 33 + f] = a.w;
            Ltr[(ds + 4) * 33 + f] = b.x; Ltr[(ds + 5) * 33 + f] = b.y;
            Ltr[(ds + 6) * 33 + f] = b.z; Ltr[(ds + 7) * 33 + f] = b.w;
            __syncthreads();
            const int dd = t >> 2, f0 = (t & 3) * 8;
            uint4 o;
            o.x = pk2(Ltr[dd * 33 + f0 + 0], Ltr[dd * 33 + f0 + 1]);
            o.y = pk2(Ltr[dd * 33 + f0 + 2], Ltr[dd * 33 + f0 + 3]);
            o.z = pk2(Ltr[dd * 33 + f0 + 4], Ltr[dd * 33 + f0 + 5]);
            o.w = pk2(Ltr[dd * 33 + f0 + 6], Ltr[dd * 33 + f0 + 7]);
            *(uint4*)(f2T + (size_t)es * (FF * DM) + (d0 + dd) * FF + f0) = o;
        }
    }
}

// ---------------------------------------------------------------------------
// K2: H = relu(x_gathered @ f1 + bias) via MFMA. LDS-free. UNCHANGED.
// ---------------------------------------------------------------------------
__global__ __launch_bounds__(256) void k_h_mfma(
    const ushort* __restrict__ xb, const ushort* __restrict__ f1F,
    const float* __restrict__ bias, const int* __restrict__ idx,
    ushort* __restrict__ Hb)
{
    const int es = blockIdx.x >> 2;
    const int gq = blockIdx.x & 3;
    const int w = threadIdx.x >> 6;
    const int lane = threadIdx.x & 63;
    const int lrow = lane & 15;
    const int lk8 = (lane >> 4) * 8;

    const int ga = gq * 64 + w * 16 + lrow;
    const int tok = idx[ga * NSLOT + es];
    const ushort* abase = xb + ((size_t)ga * TG + tok) * DM + lk8;
    const ushort* bbase = f1F + (size_t)es * 2 * 32 * 512 + (size_t)lane * 8;

    f32x4 acc[2] = {(f32x4){0.f, 0.f, 0.f, 0.f}, (f32x4){0.f, 0.f, 0.f, 0.f}};

#pragma unroll 4
    for (int kslice = 0; kslice < 32; ++kslice) {
        const bf16x8 A = *(const bf16x8*)(abase + kslice * 32);
#pragma unroll
        for (int nt = 0; nt < 2; ++nt) {
            const bf16x8 B = *(const bf16x8*)(bbase + ((size_t)nt * 32 + kslice) * 512);
            acc[nt] = __builtin_amdgcn_mfma_f32_16x16x32_bf16(A, B, acc[nt], 0, 0, 0);
        }
    }

#pragma unroll
    for (int nt = 0; nt < 2; ++nt) {
        const int f = nt * 16 + lrow;
        const float bv = bias[es * FF + f];
#pragma unroll
        for (int r = 0; r < 4; ++r) {
            const int g = gq * 64 + w * 16 + (lane >> 4) * 4 + r;
            const float hv = fmaxf(acc[nt][r] + bv, 0.0f);
            Hb[(size_t)g * (NSLOT * FF) + es * FF + f] = f2bf(hv);
        }
    }
}

// ---------------------------------------------------------------------------
// K3: v9 structure (proven 53 us, 8 groups/block, OL[8][2052], 2 blocks/CU)
// + v11 change: explicit 4-deep software pipeline. es processed in chunks
// of 4; chunk c+1's 8 global loads (A from f2T, B from Hb) are issued into
// named registers BEFORE chunk c's MFMA+RMW, hiding the ~300-500 cy L2
// latency that v9 exposed serially (VGPR=28 showed no pipelining).
// Last-chunk prefetch wraps to es 0..3 (valid addresses, values discarded).
// ---------------------------------------------------------------------------
__global__ __launch_bounds__(256) void k_out_mfma(
    const ushort* __restrict__ Hb, const ushort* __restrict__ f2T,
    const int* __restrict__ idx, float* __restrict__ out)
{
    extern __shared__ char smK3[];
    float* OL   = (float*)smK3;              // [8][2052] = 65664 B
    int* idxs_t = (int*)(smK3 + 65664);      // [128][8]  = 4096 B

    const int G0 = (blockIdx.x >> 4) * 8;
    const int D0 = (blockIdx.x & 15) * 64;
    const int tid = threadIdx.x;
    const int w = tid >> 6;
    const int lane = tid & 63;
    const int gl = lane & 15;
    const int g8 = gl & 7;
    const int lk8 = (lane >> 4) * 8;

    for (int i = tid * 4; i < 8 * 2052; i += 1024)
        *(f32x4*)&OL[i] = (f32x4){0.f, 0.f, 0.f, 0.f};
    for (int i = tid; i < NSLOT * 8; i += 256)
        idxs_t[i] = idx[(G0 + (i & 7)) * NSLOT + (i >> 3)];
    __syncthreads();

    const ushort* ap = f2T + (size_t)(D0 + w * 16 + gl) * FF + lk8;
    const ushort* bp = Hb + (size_t)(G0 + g8) * (NSLOT * FF) + lk8;
    const int dloc = w * 16 + (lane >> 4) * 4;
    float* olbase = &OL[g8 * 2052 + dloc];

    // prologue: chunk 0 in registers
    bf16x8 A0, A1, A2, A3, B0, B1, B2, B3;
    A0 = *(const bf16x8*)(ap + (size_t)0 * (FF * DM));
    A1 = *(const bf16x8*)(ap + (size_t)1 * (FF * DM));
    A2 = *(const bf16x8*)(ap + (size_t)2 * (FF * DM));
    A3 = *(const bf16x8*)(ap + (size_t)3 * (FF * DM));
    B0 = *(const bf16x8*)(bp + 0 * FF);
    B1 = *(const bf16x8*)(bp + 1 * FF);
    B2 = *(const bf16x8*)(bp + 2 * FF);
    B3 = *(const bf16x8*)(bp + 3 * FF);

    for (int c = 0; c < 32; ++c) {
        // issue next-chunk loads first (wraps to 0 on last iter; discarded)
        const int en = ((c + 1) & 31) * 4;
        bf16x8 nA0, nA1, nA2, nA3, nB0, nB1, nB2, nB3;
        nA0 = *(const bf16x8*)(ap + (size_t)(en + 0) * (FF * DM));
        nA1 = *(const bf16x8*)(ap + (size_t)(en + 1) * (FF * DM));
        nA2 = *(const bf16x8*)(ap + (size_t)(en + 2) * (FF * DM));
        nA3 = *(const bf16x8*)(ap + (size_t)(en + 3) * (FF * DM));
        nB0 = *(const bf16x8*)(bp + (en + 0) * FF);
        nB1 = *(const bf16x8*)(bp + (en + 1) * FF);
        nB2 = *(const bf16x8*)(bp + (en + 2) * FF);
        nB3 = *(const bf16x8*)(bp + (en + 3) * FF);

        const int eb = c * 4;
        {
            const f32x4 d = __builtin_amdgcn_mfma_f32_16x16x32_bf16(
                A0, B0, (f32x4){0.f, 0.f, 0.f, 0.f}, 0, 0, 0);
            float* olp = olbase + idxs_t[(eb + 0) * 8 + g8] * 64;
            *(f32x4*)olp = *(const f32x4*)olp + d;
        }
        {
            const f32x4 d = __builtin_amdgcn_mfma_f32_16x16x32_bf16(
                A1, B1, (f32x4){0.f, 0.f, 0.f, 0.f}, 0, 0, 0);
            float* olp = olbase + idxs_t[(eb + 1) * 8 + g8] * 64;
            *(f32x4*)olp = *(const f32x4*)olp + d;
        }
        {
            const f32x4 d = __builtin_amdgcn_mfma_f32_16x16x32_bf16(
                A2, B2, (f32x4){0.f, 0.f, 0.f, 0.f}, 0, 0, 0);
            float* olp = olbase + idxs_t[(eb + 2) * 8 + g8] * 64;
            *(f32x4*)olp = *(const f32x4*)olp + d;
        }
        {
            const f32x4 d = __builtin_amdgcn_mfma_f32_16x16x32_bf16(
                A3, B3, (f32x4){0.f, 0.f, 0.f, 0.f}, 0, 0, 0);
            float* olp = olbase + idxs_t[(eb + 3) * 8 + g8] * 64;
            *(f32x4*)olp = *(const f32x4*)olp + d;
        }

        A0 = nA0; A1 = nA1; A2 = nA2; A3 = nA3;
        B0 = nB0; B1 = nB1; B2 = nB2; B3 = nB3;
    }
    __syncthreads();

    // dense write-out: 8 groups x 32 t x 64 d = 16384 f32
    for (int it = 0; it < 16; ++it) {
        const int flat = tid * 4 + it * 1024;
        const int gli = flat >> 11, rem = flat & 2047;
        const int t = rem >> 6, d = rem & 63;
        const f32x4 v = *(const f32x4*)&OL[gli * 2052 + rem];
        *(f32x4*)&out[((size_t)(G0 + gli) * TG + t) * DM + D0 + d] = v;
    }
}

// ---------------------------------------------------------------------------
extern "C" void kernel_launch(void* const* d_in, const int* in_sizes, int n_in,
                              void* d_out, int out_size, void* d_ws, size_t ws_size,
                              hipStream_t stream) {
    (void)in_sizes; (void)n_in; (void)out_size; (void)ws_size;
    const float* x    = (const float*)d_in[0];
    const float* ctrl = (const float*)d_in[1];
    const float* f1   = (const float*)d_in[2];
    const float* bias = (const float*)d_in[3];
    const float* f2   = (const float*)d_in[4];
    float* out = (float*)d_out;

    char* ws = (char*)d_ws;
    int*    idx = (int*)ws;                         // 128 KB
    ushort* Hb  = (ushort*)(ws + 131072);           // 2 MB
    ushort* f1F = (ushort*)(ws + 2228224);          // 8 MB
    ushort* f2T = (ushort*)(ws + 10616832);         // 8 MB
    ushort* xb  = (ushort*)(ws + 19005440);         // 16 MB (end ~34 MB)

    k_fused1<<<1280, 256, 0, stream>>>(x, ctrl, f1, f2, idx, xb, f1F, f2T);

    k_h_mfma<<<NSLOT * 4, 256, 0, stream>>>(xb, f1F, bias, idx, Hb);

    const size_t lds3 = 65664 + 4096;               // 69760 -> 2 blocks/CU
    hipFuncSetAttribute((const void*)k_out_mfma,
                        hipFuncAttributeMaxDynamicSharedMemorySize, (int)lds3);
    k_out_mfma<<<512, 256, lds3, stream>>>(Hb, f2T, idx, out);
}

// Round 12
// 90.568 us; speedup vs baseline: 1.4721x; 1.0478x over previous
//
#include <hip/hip_runtime.h>
#include <hip/hip_bf16.h>

#define NGROUP 256   // B * (SEQ/TG)
#define NSLOT  128   // experts * sets
#define TG     32    // tokens per group
#define DM     1024  // model dim
#define FF     32    // expert size

#define LSCALE     4096.0f
#define INV_LSCALE (1.0f / 4096.0f)

typedef unsigned int  uint;
typedef unsigned short ushort;
typedef __attribute__((ext_vector_type(4))) float f32x4;
typedef __attribute__((ext_vector_type(8))) short bf16x8;
typedef __attribute__((ext_vector_type(8))) _Float16 f16x8;

__device__ __forceinline__ ushort f2bf(float f) {
    uint u = __float_as_uint(f);
    u += 0x7FFFu + ((u >> 16) & 1u);   // RNE
    return (ushort)(u >> 16);
}
__device__ __forceinline__ uint pk2(float a, float b) {
    return (uint)f2bf(a) | ((uint)f2bf(b) << 16);
}

// async global->LDS, 16B per lane; dst is wave-uniform base (+lane*16 implicit)
__device__ __forceinline__ void gload_lds16(const void* g, void* l) {
    __builtin_amdgcn_global_load_lds(
        (const __attribute__((address_space(1))) uint*)g,
        (__attribute__((address_space(3))) uint*)l, 16, 0, 0);
}

// ---------------------------------------------------------------------------
// K1 mega-kernel (unchanged from v9): one launch, three block families.
//  blocks 0..511    : logits + tie-broken argmax + fused x->bf16 cast
//  blocks 512..767  : f1 -> f1F bf16 (MFMA-B fragment order)
//  blocks 768..1279 : f2 -> f2T[es][d][f] bf16
// ---------------------------------------------------------------------------
__global__ __launch_bounds__(256) void k_fused1(
    const float* __restrict__ x, const float* __restrict__ ctrl,
    const float* __restrict__ f1, const float* __restrict__ f2,
    int* __restrict__ idx, ushort* __restrict__ xb,
    ushort* __restrict__ f1F, ushort* __restrict__ f2T)
{
    __shared__ float smem[4 * 32 * 64];   // 32 KB
    const int t = threadIdx.x;

    if (blockIdx.x < 512) {
        float* Lp = smem;
        const int g  = blockIdx.x >> 1;
        const int nh = blockIdx.x & 1;
        const int w = t >> 6;
        const int lane = t & 63;
        const int lrow = lane & 15;
        const int lk8 = (lane >> 4) * 8;

        const size_t xoff0 = ((size_t)g * TG + lrow) * DM + w * 256 + lk8;
        const float* xr0 = x + xoff0;
        const float* xr1 = xr0 + 16 * DM;

        f32x4 ahh[2][4], ax[2][4];
#pragma unroll
        for (int mt = 0; mt < 2; ++mt)
#pragma unroll
            for (int nt = 0; nt < 4; ++nt) {
                ahh[mt][nt] = (f32x4){0.f, 0.f, 0.f, 0.f};
                ax[mt][nt]  = (f32x4){0.f, 0.f, 0.f, 0.f};
            }

        for (int ks = 0; ks < 8; ++ks) {
            f16x8 Ah[2], Al[2];
#pragma unroll
            for (int mt = 0; mt < 2; ++mt) {
                const float* p = (mt ? xr1 : xr0) + ks * 32;
                float xe[8];
                *(float4*)&xe[0] = *(const float4*)p;
                *(float4*)&xe[4] = *(const float4*)(p + 4);
                union { f16x8 v; _Float16 e[8]; } H, L;
#pragma unroll
                for (int j = 0; j < 8; ++j) {
                    const _Float16 h = (_Float16)xe[j];
                    H.e[j] = h;
                    L.e[j] = (_Float16)((xe[j] - (float)h) * LSCALE);
                }
                Ah[mt] = H.v; Al[mt] = L.v;
                if (nh == 0) {
                    uint4 o;
                    o.x = pk2(xe[0], xe[1]); o.y = pk2(xe[2], xe[3]);
                    o.z = pk2(xe[4], xe[5]); o.w = pk2(xe[6], xe[7]);
                    *(uint4*)(xb + xoff0 + (size_t)mt * 16 * DM + ks * 32) = o;
                }
            }
            const int kslice = w * 8 + ks;
#pragma unroll
            for (int nt = 0; nt < 4; ++nt) {
                const float* cp = ctrl
                    + (size_t)(kslice * 32 + ((lane >> 4) << 3)) * NSLOT
                    + nh * 64 + nt * 16 + (lane & 15);
                union { f16x8 v; _Float16 e[8]; } BH, BL;
#pragma unroll
                for (int j = 0; j < 8; ++j) {
                    const float c = cp[(size_t)j * NSLOT];
                    const _Float16 h = (_Float16)c;
                    BH.e[j] = h;
                    BL.e[j] = (_Float16)((c - (float)h) * LSCALE);
                }
#pragma unroll
                for (int mt = 0; mt < 2; ++mt) {
                    ahh[mt][nt] = __builtin_amdgcn_mfma_f32_16x16x32_f16(Ah[mt], BH.v, ahh[mt][nt], 0, 0, 0);
                    ax[mt][nt]  = __builtin_amdgcn_mfma_f32_16x16x32_f16(Al[mt], BH.v, ax[mt][nt], 0, 0, 0);
                    ax[mt][nt]  = __builtin_amdgcn_mfma_f32_16x16x32_f16(Ah[mt], BL.v, ax[mt][nt], 0, 0, 0);
                }
            }
        }

#pragma unroll
        for (int mt = 0; mt < 2; ++mt)
#pragma unroll
            for (int nt = 0; nt < 4; ++nt)
#pragma unroll
                for (int r = 0; r < 4; ++r) {
                    const int trow = mt * 16 + (lane >> 4) * 4 + r;
                    const int nl = nt * 16 + lrow;
                    Lp[(w * TG + trow) * 64 + nl] =
                        ahh[mt][nt][r] + ax[mt][nt][r] * INV_LSCALE;
                }
        __syncthreads();

        for (int i = t * 4; i < TG * 64; i += 256 * 4) {
            f32x4 s0 = *(const f32x4*)&Lp[i];
            f32x4 s1 = *(const f32x4*)&Lp[2048 + i];
            f32x4 s2 = *(const f32x4*)&Lp[4096 + i];
            f32x4 s3 = *(const f32x4*)&Lp[6144 + i];
            *(f32x4*)&Lp[i] = (s0 + s1) + (s2 + s3);
        }
        __syncthreads();

        if (t < 64) {
            const int n = t;
            float best = -1e30f;
            int bi = 0;
#pragma unroll
            for (int tt = 0; tt < TG; ++tt) {
                const float v = Lp[tt * 64 + n] + (float)tt * (1e-6f / 31.0f);
                if (v >= best) { best = v; bi = tt; }   // later token wins ties
            }
            idx[g * NSLOT + nh * 64 + n] = bi;
        }
    } else if (blockIdx.x < 768) {
        float* Ltr = smem;   // [64][33]
        const int i1 = blockIdx.x - 512;
        const int es = i1 >> 1;
        const int dh = i1 & 1;
        for (int d0 = dh * 512; d0 < dh * 512 + 512; d0 += 64) {
            const int dd = t >> 2, f0 = (t & 3) * 8;
            const float* src = f1 + (size_t)(d0 + dd) * 4096 + es * FF + f0;
            float4 a = *(const float4*)src;
            float4 b = *(const float4*)(src + 4);
            __syncthreads();
            float* Lq = &Ltr[dd * 33 + f0];
            Lq[0] = a.x; Lq[1] = a.y; Lq[2] = a.z; Lq[3] = a.w;
            Lq[4] = b.x; Lq[5] = b.y; Lq[6] = b.z; Lq[7] = b.w;
            __syncthreads();
            const int f = t & 31, koct = t >> 5;
            const int nt = f >> 4;
            const int kg = d0 + koct * 8;
            const int kslice = kg >> 5;
            const int lane2 = (f & 15) | (((kg >> 3) & 3) << 4);
            uint4 o;
            o.x = pk2(Ltr[(koct * 8 + 0) * 33 + f], Ltr[(koct * 8 + 1) * 33 + f]);
            o.y = pk2(Ltr[(koct * 8 + 2) * 33 + f], Ltr[(koct * 8 + 3) * 33 + f]);
            o.z = pk2(Ltr[(koct * 8 + 4) * 33 + f], Ltr[(koct * 8 + 5) * 33 + f]);
            o.w = pk2(Ltr[(koct * 8 + 6) * 33 + f], Ltr[(koct * 8 + 7) * 33 + f]);
            *(uint4*)(f1F + ((((size_t)es * 2 + nt) * 32 + kslice) * 64 + lane2) * 8) = o;
        }
    } else {
        float* Ltr = smem;   // [64][33]
        const int i2 = blockIdx.x - 768;
        const int es = i2 >> 2;
        const int dq = i2 & 3;
        for (int d0 = dq * 256; d0 < dq * 256 + 256; d0 += 64) {
            const int f = t >> 3, ds = (t & 7) * 8;
            const float* src = f2 + (size_t)es * (FF * DM) + f * DM + d0 + ds;
            float4 a = *(const float4*)src;
            float4 b = *(const float4*)(src + 4);
            __syncthreads();
            Ltr[(ds + 0) * 33 + f] = a.x; Ltr[(ds + 1) * 33 + f] = a.y;
            Ltr[(ds + 2) * 33 + f] = a.z; Ltr[(ds + 3) * 33 + f] = a.w;
            Ltr[(ds + 4) * 33 + f] = b.x; Ltr[(ds + 5) * 33 + f] = b.y;
            Ltr[(ds + 6) * 33 + f] = b.z; Ltr[(ds + 7) * 33 + f] = b.w;
            __syncthreads();
            const int dd = t >> 2, f0 = (t & 3) * 8;
            uint4 o;
            o.x = pk2(Ltr[dd * 33 + f0 + 0], Ltr[dd * 33 + f0 + 1]);
            o.y = pk2(Ltr[dd * 33 + f0 + 2], Ltr[dd * 33 + f0 + 3]);
            o.z = pk2(Ltr[dd * 33 + f0 + 4], Ltr[dd * 33 + f0 + 5]);
            o.w = pk2(Ltr[dd * 33 + f0 + 6], Ltr[dd * 33 + f0 + 7]);
            *(uint4*)(f2T + (size_t)es * (FF * DM) + (d0 + dd) * FF + f0) = o;
        }
    }
}

// ---------------------------------------------------------------------------
// K2: H = relu(x_gathered @ f1 + bias) via MFMA. LDS-free. UNCHANGED.
// ---------------------------------------------------------------------------
__global__ __launch_bounds__(256) void k_h_mfma(
    const ushort* __restrict__ xb, const ushort* __restrict__ f1F,
    const float* __restrict__ bias, const int* __restrict__ idx,
    ushort* __restrict__ Hb)
{
    const int es = blockIdx.x >> 2;
    const int gq = blockIdx.x & 3;
    const int w = threadIdx.x >> 6;
    const int lane = threadIdx.x & 63;
    const int lrow = lane & 15;
    const int lk8 = (lane >> 4) * 8;

    const int ga = gq * 64 + w * 16 + lrow;
    const int tok = idx[ga * NSLOT + es];
    const ushort* abase = xb + ((size_t)ga * TG + tok) * DM + lk8;
    const ushort* bbase = f1F + (size_t)es * 2 * 32 * 512 + (size_t)lane * 8;

    f32x4 acc[2] = {(f32x4){0.f, 0.f, 0.f, 0.f}, (f32x4){0.f, 0.f, 0.f, 0.f}};

#pragma unroll 4
    for (int kslice = 0; kslice < 32; ++kslice) {
        const bf16x8 A = *(const bf16x8*)(abase + kslice * 32);
#pragma unroll
        for (int nt = 0; nt < 2; ++nt) {
            const bf16x8 B = *(const bf16x8*)(bbase + ((size_t)nt * 32 + kslice) * 512);
            acc[nt] = __builtin_amdgcn_mfma_f32_16x16x32_bf16(A, B, acc[nt], 0, 0, 0);
        }
    }

#pragma unroll
    for (int nt = 0; nt < 2; ++nt) {
        const int f = nt * 16 + lrow;
        const float bv = bias[es * FF + f];
#pragma unroll
        for (int r = 0; r < 4; ++r) {
            const int g = gq * 64 + w * 16 + (lane >> 4) * 4 + r;
            const float hv = fmaxf(acc[nt][r] + bv, 0.0f);
            Hb[(size_t)g * (NSLOT * FF) + es * FF + f] = f2bf(hv);
        }
    }
}

// ---------------------------------------------------------------------------
// K3 (v12): v9 geometry (8 groups x 64 d, OL[8][2052], dup x2) with ALL main-
// loop global loads removed from the register path:
//  - B (Hb slice, 8 rows) + idx staged ONCE into LDS at block start.
//  - A (f2T slab, 1 KB/wave/es) staged through a 6-deep per-wave LDS ring via
//    global_load_lds (no dest regs -> compiler cannot insert vmcnt(0) drains);
//    hand-placed s_waitcnt vmcnt(5). Per-lane global source = the lane's own
//    consumer segment -> consumer ds_read_b128 at lane*16, conflict-free.
// LDS = 160000 B exactly -> 1 block/CU, grid 512 (2 rounds).
// Tail: stages wrap to early es into slots whose last read already passed.
// ---------------------------------------------------------------------------
__global__ __launch_bounds__(256) void k_out_mfma(
    const ushort* __restrict__ Hb, const ushort* __restrict__ f2T,
    const int* __restrict__ idx, float* __restrict__ out)
{
    extern __shared__ char smK3[];
    float*  OL    = (float*)smK3;                  // [8][2052] = 65664 B
    ushort* Bfull = (ushort*)(smK3 + 65664);       // [8][4104] = 65664 B (padded)
    int*    idxs  = (int*)(smK3 + 131328);         // [128][8]  = 4096 B
    char*   Aring = smK3 + 135424;                 // [4][6][1024] = 24576 B

    const int G0 = (blockIdx.x >> 4) * 8;
    const int D0 = (blockIdx.x & 15) * 64;
    const int tid = threadIdx.x;
    const int w = tid >> 6;
    const int lane = tid & 63;
    const int gl = lane & 15;
    const int g8 = gl & 7;
    const int lk8 = (lane >> 4) * 8;

    // zero OL
    for (int i = tid * 4; i < 8 * 2052; i += 1024)
        *(f32x4*)&OL[i] = (f32x4){0.f, 0.f, 0.f, 0.f};
    // stage idx (transposed)
    for (int i = tid; i < NSLOT * 8; i += 256)
        idxs[i] = idx[(G0 + (i & 7)) * NSLOT + (i >> 3)];
    // stage full Hb slice for the 8 groups (64 KB), padded rows (+8 ushort)
#pragma unroll
    for (int it = 0; it < 16; ++it) {
        const int v8 = (tid + it * 256) * 8;          // ushort index
        const int gr = v8 >> 12;                      // group row 0..7
        const int rem = v8 & 4095;
        const uint4 q = *(const uint4*)(Hb + (size_t)(G0 + gr) * (NSLOT * FF) + rem);
        *(uint4*)(Bfull + gr * 4104 + rem) = q;
    }
    __syncthreads();

    // per-wave A ring: slot s at Aring + w*6144 + s*1024; lane segment = lane*16
    const ushort* ap = f2T + (size_t)(D0 + w * 16 + gl) * FF + lk8;  // per-lane src
    char* ring = Aring + w * 6144;

    // prologue: stage es 0..4
#pragma unroll
    for (int e = 0; e < 5; ++e)
        gload_lds16(ap + (size_t)e * (FF * DM), ring + (e % 6) * 1024);

    const int dloc = w * 16 + (lane >> 4) * 4;
    float* olbase = &OL[g8 * 2052 + dloc];
    const ushort* bfp = Bfull + g8 * 4104 + lk8;

    for (int e = 0; e < 128; ++e) {
        // stage e+5 (wraps past 127 into dead slots; keeps vmcnt pattern constant)
        gload_lds16(ap + (size_t)((e + 5) & 127) * (FF * DM),
                    ring + ((e + 5) % 6) * 1024);
        asm volatile("s_waitcnt vmcnt(5)" ::: "memory");   // slot e ready

        const bf16x8 afr = *(const bf16x8*)(ring + (e % 6) * 1024 + lane * 16);
        const bf16x8 bfr = *(const bf16x8*)(bfp + e * FF);
        const f32x4 d = __builtin_amdgcn_mfma_f32_16x16x32_bf16(
            afr, bfr, (f32x4){0.f, 0.f, 0.f, 0.f}, 0, 0, 0);
        const int t = idxs[e * 8 + g8];
        float* olp = olbase + t * 64;
        *(f32x4*)olp = *(const f32x4*)olp + d;
    }
    asm volatile("s_waitcnt vmcnt(0)" ::: "memory");
    __syncthreads();

    // dense write-out: 8 groups x 32 t x 64 d = 16384 f32
    for (int it = 0; it < 16; ++it) {
        const int flat = tid * 4 + it * 1024;
        const int gli = flat >> 11, rem = flat & 2047;
        const int t = rem >> 6, d = rem & 63;
        const f32x4 v = *(const f32x4*)&OL[gli * 2052 + rem];
        *(f32x4*)&out[((size_t)(G0 + gli) * TG + t) * DM + D0 + d] = v;
    }
}

// ---------------------------------------------------------------------------
extern "C" void kernel_launch(void* const* d_in, const int* in_sizes, int n_in,
                              void* d_out, int out_size, void* d_ws, size_t ws_size,
                              hipStream_t stream) {
    (void)in_sizes; (void)n_in; (void)out_size; (void)ws_size;
    const float* x    = (const float*)d_in[0];
    const float* ctrl = (const float*)d_in[1];
    const float* f1   = (const float*)d_in[2];
    const float* bias = (const float*)d_in[3];
    const float* f2   = (const float*)d_in[4];
    float* out = (float*)d_out;

    char* ws = (char*)d_ws;
    int*    idx = (int*)ws;                         // 128 KB
    ushort* Hb  = (ushort*)(ws + 131072);           // 2 MB
    ushort* f1F = (ushort*)(ws + 2228224);          // 8 MB
    ushort* f2T = (ushort*)(ws + 10616832);         // 8 MB
    ushort* xb  = (ushort*)(ws + 19005440);         // 16 MB (end ~34 MB)

    k_fused1<<<1280, 256, 0, stream>>>(x, ctrl, f1, f2, idx, xb, f1F, f2T);

    k_h_mfma<<<NSLOT * 4, 256, 0, stream>>>(xb, f1F, bias, idx, Hb);

    const size_t lds3 = 160000;                     // 1 block/CU by design
    hipFuncSetAttribute((const void*)k_out_mfma,
                        hipFuncAttributeMaxDynamicSharedMemorySize, (int)lds3);
    k_out_mfma<<<512, 256, lds3, stream>>>(Hb, f2T, idx, out);
}

// Round 13
// 84.229 us; speedup vs baseline: 1.5829x; 1.0753x over previous
//
#include <hip/hip_runtime.h>
#include <hip/hip_bf16.h>

#define NGROUP 256   // B * (SEQ/TG)
#define NSLOT  128   // experts * sets
#define TG     32    // tokens per group
#define DM     1024  // model dim
#define FF     32    // expert size

#define LSCALE     4096.0f
#define INV_LSCALE (1.0f / 4096.0f)

typedef unsigned int  uint;
typedef unsigned short ushort;
typedef unsigned char uchar;
typedef __attribute__((ext_vector_type(4))) float f32x4;
typedef __attribute__((ext_vector_type(8))) short bf16x8;
typedef __attribute__((ext_vector_type(8))) _Float16 f16x8;

__device__ __forceinline__ ushort f2bf(float f) {
    uint u = __float_as_uint(f);
    u += 0x7FFFu + ((u >> 16) & 1u);   // RNE
    return (ushort)(u >> 16);
}
__device__ __forceinline__ uint pk2(float a, float b) {
    return (uint)f2bf(a) | ((uint)f2bf(b) << 16);
}

// async global->LDS, 16B per lane; dst wave-uniform base (+lane*16 implicit)
__device__ __forceinline__ void gload_lds16(const void* g, void* l) {
    __builtin_amdgcn_global_load_lds(
        (const __attribute__((address_space(1))) uint*)g,
        (__attribute__((address_space(3))) uint*)l, 16, 0, 0);
}

// ---------------------------------------------------------------------------
// K1 mega-kernel (v9-proven): one launch, three block families.
//  blocks 0..511    : logits + tie-broken argmax + fused x->bf16 cast
//                     (now ALSO writes idx8 u8 copy for k_out)
//  blocks 512..767  : f1 -> f1F bf16 (MFMA-B fragment order)
//  blocks 768..1279 : f2 -> f2T[es][d][f] bf16
// ---------------------------------------------------------------------------
__global__ __launch_bounds__(256) void k_fused1(
    const float* __restrict__ x, const float* __restrict__ ctrl,
    const float* __restrict__ f1, const float* __restrict__ f2,
    int* __restrict__ idx, uchar* __restrict__ idx8, ushort* __restrict__ xb,
    ushort* __restrict__ f1F, ushort* __restrict__ f2T)
{
    __shared__ float smem[4 * 32 * 64];   // 32 KB
    const int t = threadIdx.x;

    if (blockIdx.x < 512) {
        float* Lp = smem;
        const int g  = blockIdx.x >> 1;
        const int nh = blockIdx.x & 1;
        const int w = t >> 6;
        const int lane = t & 63;
        const int lrow = lane & 15;
        const int lk8 = (lane >> 4) * 8;

        const size_t xoff0 = ((size_t)g * TG + lrow) * DM + w * 256 + lk8;
        const float* xr0 = x + xoff0;
        const float* xr1 = xr0 + 16 * DM;

        f32x4 ahh[2][4], ax[2][4];
#pragma unroll
        for (int mt = 0; mt < 2; ++mt)
#pragma unroll
            for (int nt = 0; nt < 4; ++nt) {
                ahh[mt][nt] = (f32x4){0.f, 0.f, 0.f, 0.f};
                ax[mt][nt]  = (f32x4){0.f, 0.f, 0.f, 0.f};
            }

        for (int ks = 0; ks < 8; ++ks) {
            f16x8 Ah[2], Al[2];
#pragma unroll
            for (int mt = 0; mt < 2; ++mt) {
                const float* p = (mt ? xr1 : xr0) + ks * 32;
                float xe[8];
                *(float4*)&xe[0] = *(const float4*)p;
                *(float4*)&xe[4] = *(const float4*)(p + 4);
                union { f16x8 v; _Float16 e[8]; } H, L;
#pragma unroll
                for (int j = 0; j < 8; ++j) {
                    const _Float16 h = (_Float16)xe[j];
                    H.e[j] = h;
                    L.e[j] = (_Float16)((xe[j] - (float)h) * LSCALE);
                }
                Ah[mt] = H.v; Al[mt] = L.v;
                if (nh == 0) {
                    uint4 o;
                    o.x = pk2(xe[0], xe[1]); o.y = pk2(xe[2], xe[3]);
                    o.z = pk2(xe[4], xe[5]); o.w = pk2(xe[6], xe[7]);
                    *(uint4*)(xb + xoff0 + (size_t)mt * 16 * DM + ks * 32) = o;
                }
            }
            const int kslice = w * 8 + ks;
#pragma unroll
            for (int nt = 0; nt < 4; ++nt) {
                const float* cp = ctrl
                    + (size_t)(kslice * 32 + ((lane >> 4) << 3)) * NSLOT
                    + nh * 64 + nt * 16 + (lane & 15);
                union { f16x8 v; _Float16 e[8]; } BH, BL;
#pragma unroll
                for (int j = 0; j < 8; ++j) {
                    const float c = cp[(size_t)j * NSLOT];
                    const _Float16 h = (_Float16)c;
                    BH.e[j] = h;
                    BL.e[j] = (_Float16)((c - (float)h) * LSCALE);
                }
#pragma unroll
                for (int mt = 0; mt < 2; ++mt) {
                    ahh[mt][nt] = __builtin_amdgcn_mfma_f32_16x16x32_f16(Ah[mt], BH.v, ahh[mt][nt], 0, 0, 0);
                    ax[mt][nt]  = __builtin_amdgcn_mfma_f32_16x16x32_f16(Al[mt], BH.v, ax[mt][nt], 0, 0, 0);
                    ax[mt][nt]  = __builtin_amdgcn_mfma_f32_16x16x32_f16(Ah[mt], BL.v, ax[mt][nt], 0, 0, 0);
                }
            }
        }

#pragma unroll
        for (int mt = 0; mt < 2; ++mt)
#pragma unroll
            for (int nt = 0; nt < 4; ++nt)
#pragma unroll
                for (int r = 0; r < 4; ++r) {
                    const int trow = mt * 16 + (lane >> 4) * 4 + r;
                    const int nl = nt * 16 + lrow;
                    Lp[(w * TG + trow) * 64 + nl] =
                        ahh[mt][nt][r] + ax[mt][nt][r] * INV_LSCALE;
                }
        __syncthreads();

        for (int i = t * 4; i < TG * 64; i += 256 * 4) {
            f32x4 s0 = *(const f32x4*)&Lp[i];
            f32x4 s1 = *(const f32x4*)&Lp[2048 + i];
            f32x4 s2 = *(const f32x4*)&Lp[4096 + i];
            f32x4 s3 = *(const f32x4*)&Lp[6144 + i];
            *(f32x4*)&Lp[i] = (s0 + s1) + (s2 + s3);
        }
        __syncthreads();

        if (t < 64) {
            const int n = t;
            float best = -1e30f;
            int bi = 0;
#pragma unroll
            for (int tt = 0; tt < TG; ++tt) {
                const float v = Lp[tt * 64 + n] + (float)tt * (1e-6f / 31.0f);
                if (v >= best) { best = v; bi = tt; }   // later token wins ties
            }
            idx[g * NSLOT + nh * 64 + n] = bi;
            idx8[g * NSLOT + nh * 64 + n] = (uchar)bi;
        }
    } else if (blockIdx.x < 768) {
        float* Ltr = smem;   // [64][33]
        const int i1 = blockIdx.x - 512;
        const int es = i1 >> 1;
        const int dh = i1 & 1;
        for (int d0 = dh * 512; d0 < dh * 512 + 512; d0 += 64) {
            const int dd = t >> 2, f0 = (t & 3) * 8;
            const float* src = f1 + (size_t)(d0 + dd) * 4096 + es * FF + f0;
            float4 a = *(const float4*)src;
            float4 b = *(const float4*)(src + 4);
            __syncthreads();
            float* Lq = &Ltr[dd * 33 + f0];
            Lq[0] = a.x; Lq[1] = a.y; Lq[2] = a.z; Lq[3] = a.w;
            Lq[4] = b.x; Lq[5] = b.y; Lq[6] = b.z; Lq[7] = b.w;
            __syncthreads();
            const int f = t & 31, koct = t >> 5;
            const int nt = f >> 4;
            const int kg = d0 + koct * 8;
            const int kslice = kg >> 5;
            const int lane2 = (f & 15) | (((kg >> 3) & 3) << 4);
            uint4 o;
            o.x = pk2(Ltr[(koct * 8 + 0) * 33 + f], Ltr[(koct * 8 + 1) * 33 + f]);
            o.y = pk2(Ltr[(koct * 8 + 2) * 33 + f], Ltr[(koct * 8 + 3) * 33 + f]);
            o.z = pk2(Ltr[(koct * 8 + 4) * 33 + f], Ltr[(koct * 8 + 5) * 33 + f]);
            o.w = pk2(Ltr[(koct * 8 + 6) * 33 + f], Ltr[(koct * 8 + 7) * 33 + f]);
            *(uint4*)(f1F + ((((size_t)es * 2 + nt) * 32 + kslice) * 64 + lane2) * 8) = o;
        }
    } else {
        float* Ltr = smem;   // [64][33]
        const int i2 = blockIdx.x - 768;
        const int es = i2 >> 2;
        const int dq = i2 & 3;
        for (int d0 = dq * 256; d0 < dq * 256 + 256; d0 += 64) {
            const int f = t >> 3, ds = (t & 7) * 8;
            const float* src = f2 + (size_t)es * (FF * DM) + f * DM + d0 + ds;
            float4 a = *(const float4*)src;
            float4 b = *(const float4*)(src + 4);
            __syncthreads();
            Ltr[(ds + 0) * 33 + f] = a.x; Ltr[(ds + 1) * 33 + f] = a.y;
            Ltr[(ds + 2) * 33 + f] = a.z; Ltr[(ds + 3) * 33 + f] = a.w;
            Ltr[(ds + 4) * 33 + f] = b.x; Ltr[(ds + 5) * 33 + f] = b.y;
            Ltr[(ds + 6) * 33 + f] = b.z; Ltr[(ds + 7) * 33 + f] = b.w;
            __syncthreads();
            const int dd = t >> 2, f0 = (t & 3) * 8;
            uint4 o;
            o.x = pk2(Ltr[dd * 33 + f0 + 0], Ltr[dd * 33 + f0 + 1]);
            o.y = pk2(Ltr[dd * 33 + f0 + 2], Ltr[dd * 33 + f0 + 3]);
            o.z = pk2(Ltr[dd * 33 + f0 + 4], Ltr[dd * 33 + f0 + 5]);
            o.w = pk2(Ltr[dd * 33 + f0 + 6], Ltr[dd * 33 + f0 + 7]);
            *(uint4*)(f2T + (size_t)es * (FF * DM) + (d0 + dd) * FF + f0) = o;
        }
    }
}

// ---------------------------------------------------------------------------
// K2: H = relu(x_gathered @ f1 + bias) via MFMA. LDS-free. UNCHANGED.
// ---------------------------------------------------------------------------
__global__ __launch_bounds__(256) void k_h_mfma(
    const ushort* __restrict__ xb, const ushort* __restrict__ f1F,
    const float* __restrict__ bias, const int* __restrict__ idx,
    ushort* __restrict__ Hb)
{
    const int es = blockIdx.x >> 2;
    const int gq = blockIdx.x & 3;
    const int w = threadIdx.x >> 6;
    const int lane = threadIdx.x & 63;
    const int lrow = lane & 15;
    const int lk8 = (lane >> 4) * 8;

    const int ga = gq * 64 + w * 16 + lrow;
    const int tok = idx[ga * NSLOT + es];
    const ushort* abase = xb + ((size_t)ga * TG + tok) * DM + lk8;
    const ushort* bbase = f1F + (size_t)es * 2 * 32 * 512 + (size_t)lane * 8;

    f32x4 acc[2] = {(f32x4){0.f, 0.f, 0.f, 0.f}, (f32x4){0.f, 0.f, 0.f, 0.f}};

#pragma unroll 4
    for (int kslice = 0; kslice < 32; ++kslice) {
        const bf16x8 A = *(const bf16x8*)(abase + kslice * 32);
#pragma unroll
        for (int nt = 0; nt < 2; ++nt) {
            const bf16x8 B = *(const bf16x8*)(bbase + ((size_t)nt * 32 + kslice) * 512);
            acc[nt] = __builtin_amdgcn_mfma_f32_16x16x32_bf16(A, B, acc[nt], 0, 0, 0);
        }
    }

#pragma unroll
    for (int nt = 0; nt < 2; ++nt) {
        const int f = nt * 16 + lrow;
        const float bv = bias[es * FF + f];
#pragma unroll
        for (int r = 0; r < 4; ++r) {
            const int g = gq * 64 + w * 16 + (lane >> 4) * 4 + r;
            const float hv = fmaxf(acc[nt][r] + bv, 0.0f);
            Hb[(size_t)g * (NSLOT * FF) + es * FF + f] = f2bf(hv);
        }
    }
}

// ---------------------------------------------------------------------------
// K3 (v13): v12 ring structure, upgraded:
//  - 2 es per iteration, ring = 4 slots x 2KB/wave -> 6 es in flight, vmcnt(6)
//  - Bfull + OL unpadded 64K each with XOR swizzle (16B slot s^g8 / quad q^g8)
//    -> conflict-free staging, B-reads, RMW, epilogue (b128-optimal 4/bank)
//  - idx8 preloaded into 32 registers/lane, es-loop fully unrolled (static idx)
// LDS = 65536 + 65536 + 32768 = 163840 (full CU LDS; AITER uses 160KB/wg).
// ---------------------------------------------------------------------------
__global__ __launch_bounds__(256) void k_out_mfma(
    const ushort* __restrict__ Hb, const ushort* __restrict__ f2T,
    const uchar* __restrict__ idx8, float* __restrict__ out)
{
    extern __shared__ char smK3[];
    float*  OL    = (float*)smK3;                  // [8][2048] f32, quad-swizzled
    char*   Bfull = smK3 + 65536;                  // [8][512] 16B-slots, swizzled
    char*   Aring = smK3 + 131072;                 // [4 waves][4 slots][2048 B]

    const int G0 = (blockIdx.x >> 4) * 8;
    const int D0 = (blockIdx.x & 15) * 64;
    const int tid = threadIdx.x;
    const int w = tid >> 6;
    const int lane = tid & 63;
    const int gl = lane & 15;
    const int g8 = gl & 7;
    const int lk8 = (lane >> 4) * 8;

    // zero OL
    for (int i = tid * 4; i < 8 * 2048; i += 1024)
        *(f32x4*)&OL[i] = (f32x4){0.f, 0.f, 0.f, 0.f};
    // stage Bfull swizzled: row g8, 16B-slot s -> phys slot s^g8
#pragma unroll
    for (int it = 0; it < 16; ++it) {
        const int v8 = (tid + it * 256) * 8;          // ushort index
        const int gr = v8 >> 12;
        const int rem = v8 & 4095;
        const int s = rem >> 3;
        const uint4 q = *(const uint4*)(Hb + (size_t)(G0 + gr) * (NSLOT * FF) + rem);
        *(uint4*)(Bfull + gr * 8192 + ((s ^ gr) << 4)) = q;
    }
    // preload idx8 row for this lane's group: 128 bytes -> 32 regs
    uint ui[32];
    {
        const uint4* p = (const uint4*)(idx8 + (size_t)(G0 + g8) * NSLOT);
#pragma unroll
        for (int k = 0; k < 8; ++k) {
            const uint4 v = p[k];
            ui[k * 4 + 0] = v.x; ui[k * 4 + 1] = v.y;
            ui[k * 4 + 2] = v.z; ui[k * 4 + 3] = v.w;
        }
    }
    __syncthreads();

    const ushort* ap = f2T + (size_t)(D0 + w * 16 + gl) * FF + lk8;  // per-lane src
    char* ring = Aring + w * 8192;

    // prologue: slots 0..2 <- es {0,1},{2,3},{4,5}  (6 loads outstanding)
#pragma unroll
    for (int s = 0; s < 3; ++s) {
        gload_lds16(ap + (size_t)(2 * s)     * (FF * DM), ring + s * 2048);
        gload_lds16(ap + (size_t)(2 * s + 1) * (FF * DM), ring + s * 2048 + 1024);
    }

    float* olrow = &OL[g8 * 2048];
    const int qbase = w * 4 + (lane >> 4);
    const char* bfrow = Bfull + g8 * 8192;
    const int sq = lk8 >> 3;   // 16B slot within the es row (0..3)

#pragma unroll
    for (int c = 0; c < 64; ++c) {
        const int sl = (c + 3) & 3;
        const int e2 = ((c + 3) & 63) * 2;   // wraps to dummy stages at tail
        gload_lds16(ap + (size_t)e2       * (FF * DM), ring + sl * 2048);
        gload_lds16(ap + (size_t)(e2 + 1) * (FF * DM), ring + sl * 2048 + 1024);
        asm volatile("s_waitcnt vmcnt(6)" ::: "memory");   // slot c ready

        const char* slot = ring + (c & 3) * 2048;
#pragma unroll
        for (int h = 0; h < 2; ++h) {
            const int e = c * 2 + h;
            const bf16x8 afr = *(const bf16x8*)(slot + h * 1024 + lane * 16);
            const int sB = e * 4 + sq;
            const bf16x8 bfr = *(const bf16x8*)(bfrow + ((sB ^ g8) << 4));
            const f32x4 d = __builtin_amdgcn_mfma_f32_16x16x32_bf16(
                afr, bfr, (f32x4){0.f, 0.f, 0.f, 0.f}, 0, 0, 0);
            const uint tv = (ui[e >> 2] >> ((e & 3) * 8)) & 0xFFu;
            const int q = (int)tv * 16 + qbase;
            float* olp = olrow + ((q ^ g8) << 2);
            *(f32x4*)olp = *(const f32x4*)olp + d;
        }
    }
    asm volatile("s_waitcnt vmcnt(0)" ::: "memory");
    __syncthreads();

    // dense write-out: logical (gli, t, d) from physical quad (q ^ gli)
    for (int it = 0; it < 16; ++it) {
        const int flat = tid * 4 + it * 1024;
        const int gli = flat >> 11, rem = flat & 2047;
        const int t = rem >> 6, d = rem & 63;
        const int q = rem >> 2;
        const f32x4 v = *(const f32x4*)&OL[gli * 2048 + ((q ^ gli) << 2)];
        *(f32x4*)&out[((size_t)(G0 + gli) * TG + t) * DM + D0 + d] = v;
    }
}

// ---------------------------------------------------------------------------
extern "C" void kernel_launch(void* const* d_in, const int* in_sizes, int n_in,
                              void* d_out, int out_size, void* d_ws, size_t ws_size,
                              hipStream_t stream) {
    (void)in_sizes; (void)n_in; (void)out_size; (void)ws_size;
    const float* x    = (const float*)d_in[0];
    const float* ctrl = (const float*)d_in[1];
    const float* f1   = (const float*)d_in[2];
    const float* bias = (const float*)d_in[3];
    const float* f2   = (const float*)d_in[4];
    float* out = (float*)d_out;

    char* ws = (char*)d_ws;
    int*    idx  = (int*)ws;                        // 128 KB
    ushort* Hb   = (ushort*)(ws + 131072);          // 2 MB
    ushort* f1F  = (ushort*)(ws + 2228224);         // 8 MB
    ushort* f2T  = (ushort*)(ws + 10616832);        // 8 MB
    ushort* xb   = (ushort*)(ws + 19005440);        // 16 MB
    uchar*  idx8 = (uchar*)(ws + 35782656);         // 32 KB (end ~34.2 MB)

    k_fused1<<<1280, 256, 0, stream>>>(x, ctrl, f1, f2, idx, idx8, xb, f1F, f2T);

    k_h_mfma<<<NSLOT * 4, 256, 0, stream>>>(xb, f1F, bias, idx, Hb);

    const size_t lds3 = 163840;                     // full CU LDS
    hipFuncSetAttribute((const void*)k_out_mfma,
                        hipFuncAttributeMaxDynamicSharedMemorySize, (int)lds3);
    k_out_mfma<<<512, 256, lds3, stream>>>(Hb, f2T, idx8, out);
}